// Round 4
// baseline (402.006 us; speedup 1.0000x reference)
//
#include <hip/hip_runtime.h>
#include <math.h>

// Problem constants (fixed by setup_inputs)
#define M 8192
#define N 256
#define K 7168
#define N_GROUPS 8
#define TOPK 8
#define ROUTE_SCALE 2.5f

// GEMM tiling
#define BM 64
#define BN 128
#define BK 64
// K-split 3: 112 K-steps of 64 split 38/37/37 -> grid 768 = 3 blocks/CU

typedef _Float16 half8 __attribute__((ext_vector_type(8)));
typedef _Float16 half4 __attribute__((ext_vector_type(4)));
typedef float f32x4 __attribute__((ext_vector_type(4)));

// global -> LDS direct copy, 16B per lane; LDS dest = wave-uniform base + lane*16
__device__ __forceinline__ void gload_lds16(const void* g, void* l) {
    __builtin_amdgcn_global_load_lds(
        (const __attribute__((address_space(1))) unsigned int*)g,
        (__attribute__((address_space(3))) unsigned int*)l,
        16, 0, 0);
}

// ---------------------------------------------------------------------------
// Kernel Z: zero the accumulator buffer P (ws is re-poisoned 0xAA every call)
// ---------------------------------------------------------------------------
__global__ __launch_bounds__(256) void zero_p(float4* __restrict__ P) {
    P[blockIdx.x * 256 + threadIdx.x] = float4{0.f, 0.f, 0.f, 0.f};
}

// ---------------------------------------------------------------------------
// Kernel 0: split W (fp32) into fp16 hi + fp16 residual lo. 7.3 MB, ~4 us.
// ---------------------------------------------------------------------------
__global__ __launch_bounds__(256) void convert_w(
        const float* __restrict__ W, _Float16* __restrict__ Wh,
        _Float16* __restrict__ Wl) {
    const int idx = blockIdx.x * 256 + threadIdx.x;   // float4 index
    const float4 w = ((const float4*)W)[idx];
    const float e[4] = {w.x, w.y, w.z, w.w};
    half4 h, l;
#pragma unroll
    for (int j = 0; j < 4; ++j) {
        const _Float16 hv = (_Float16)e[j];
        h[j] = hv;
        l[j] = (_Float16)(e[j] - (float)hv);
    }
    ((half4*)Wh)[idx] = h;
    ((half4*)Wl)[idx] = l;
}

// ---------------------------------------------------------------------------
// Kernel 1: P[m][n] += sum_{k in split ks} x[m,k]*W[n,k]  (atomicAdd epilogue)
// via 3-term fp16 split MFMA: xh*wh + xh*wl + xl*wh  (~1e-7 of fp32).
// LDS tiles [rows][64 f16], 16B-chunk c of row r stored at chunk c^(r&7)
// (XOR swizzle, both write and read sides).
// ---------------------------------------------------------------------------
__global__ __launch_bounds__(256, 3) void gemm_split(
        const float* __restrict__ X,      // [M,K] fp32
        const _Float16* __restrict__ Wh,  // [N,K] f16 hi
        const _Float16* __restrict__ Wl,  // [N,K] f16 lo
        float* __restrict__ P) {          // [M,N] logits accumulator
    __shared__ _Float16 Ah[BM][BK], Al[BM][BK];   // 8 KB each
    __shared__ _Float16 Bh[BN][BK], Bl[BN][BK];   // 16 KB each -> 48 KB total

    const int tid = threadIdx.x;
    const int bid = blockIdx.x;
    // Decode: xcd = bid&7 (HW round-robin). nb-pair (same X-slab) differs only
    // in bit 3 -> same XCD, adjacent dispatch -> X slab read once via L2.
    const int x3 = bid & 7;
    const int nb = (bid >> 3) & 1;
    const int r = bid >> 4;               // 0..47
    const int ks = r % 3;                 // K-split index
    const int mb = ((r / 3) << 3) | x3;   // 0..127
    const int m0 = mb * BM, n0 = nb * BN;
    const int kstart = (ks == 0) ? 0 : (ks == 1 ? 38 : 75);   // in BK units
    const int nsteps = (ks == 0) ? 38 : 37;

    const int lane = tid & 63, wave = tid >> 6;
    const int wr = wave >> 1, wc = wave & 1;       // wave grid 2x2
    const int lrow = lane & 15, lkq = lane >> 4;   // fragment coords

    // B staging (global_load_lds): wave-issue covers 8 rows (64 lanes x 16B)
    const int blr = lane >> 3;                 // row within 8-row chunk
    const int bcsw = (lane & 7) ^ blr;         // pre-swizzled source chunk

    // A staging (reg: fp32 -> f16 hi/lo): thread owns row ar, chunks ac0,ac0+1
    const int ar = tid >> 2;
    const int ac0 = (tid & 3) << 1;

    f32x4 acc[2][4];
#pragma unroll
    for (int i = 0; i < 2; ++i)
#pragma unroll
        for (int j = 0; j < 4; ++j) acc[i][j] = (f32x4){0.f, 0.f, 0.f, 0.f};

    const float* Abase = X + (size_t)(m0 + ar) * K + ac0 * 8;
    const _Float16* Whb = Wh + bcsw * 8;
    const _Float16* Wlb = Wl + bcsw * 8;

    for (int t = 0; t < nsteps; ++t) {
        const int k0 = (kstart + t) * BK;
        __syncthreads();   // previous iteration's readers done
        // ---- B: 4 issues/wave for hi and lo (16B/lane, linear LDS dest,
        //      swizzle achieved by pre-swizzled global source chunk)
#pragma unroll
        for (int i = 0; i < 4; ++i) {
            const int r8 = wave * 4 + i;           // 8-row chunk 0..15
            const int lr = r8 * 8 + blr;           // 0..127
            const size_t go = (size_t)(n0 + lr) * K + k0;
            gload_lds16(Whb + go, &Bh[r8 * 8][0]);
            gload_lds16(Wlb + go, &Bl[r8 * 8][0]);
        }
        // ---- A: 16 fp32 -> 2x(8 f16 hi + 8 f16 lo), swizzled ds_write_b128
        const float* ga = Abase + k0;
        float4 f[4];
#pragma unroll
        for (int i = 0; i < 4; ++i) f[i] = ((const float4*)ga)[i];
#pragma unroll
        for (int c = 0; c < 2; ++c) {
            const float e[8] = {f[c*2].x, f[c*2].y, f[c*2].z, f[c*2].w,
                                f[c*2+1].x, f[c*2+1].y, f[c*2+1].z, f[c*2+1].w};
            half8 h, l;
#pragma unroll
            for (int j = 0; j < 8; ++j) {
                const _Float16 hv = (_Float16)e[j];
                h[j] = hv;
                l[j] = (_Float16)(e[j] - (float)hv);
            }
            const int p = (ac0 + c) ^ (ar & 7);
            *(half8*)&Ah[ar][p * 8] = h;
            *(half8*)&Al[ar][p * 8] = l;
        }
        __syncthreads();   // drains global_load_lds (vmcnt) + ds_write (lgkm)

        // ---- compute: per wave 48 MFMA, 24 ds_read_b128 per K-step
#pragma unroll
        for (int s = 0; s < 2; ++s) {
            const int pc8 = ((s * 4 + lkq) ^ (lrow & 7)) * 8;  // swizzled chunk
            const half8 ah0 = *(const half8*)&Ah[wr*32 + lrow][pc8];
            const half8 ah1 = *(const half8*)&Ah[wr*32 + 16 + lrow][pc8];
            const half8 al0 = *(const half8*)&Al[wr*32 + lrow][pc8];
            const half8 al1 = *(const half8*)&Al[wr*32 + 16 + lrow][pc8];
#pragma unroll
            for (int j = 0; j < 4; ++j) {
                const int br = wc*64 + j*16 + lrow;
                const half8 bh = *(const half8*)&Bh[br][pc8];
                const half8 bl = *(const half8*)&Bl[br][pc8];
                acc[0][j] = __builtin_amdgcn_mfma_f32_16x16x32_f16(ah0, bh, acc[0][j], 0, 0, 0);
                acc[1][j] = __builtin_amdgcn_mfma_f32_16x16x32_f16(ah1, bh, acc[1][j], 0, 0, 0);
                acc[0][j] = __builtin_amdgcn_mfma_f32_16x16x32_f16(ah0, bl, acc[0][j], 0, 0, 0);
                acc[1][j] = __builtin_amdgcn_mfma_f32_16x16x32_f16(ah1, bl, acc[1][j], 0, 0, 0);
                acc[0][j] = __builtin_amdgcn_mfma_f32_16x16x32_f16(al0, bh, acc[0][j], 0, 0, 0);
                acc[1][j] = __builtin_amdgcn_mfma_f32_16x16x32_f16(al1, bh, acc[1][j], 0, 0, 0);
            }
        }
    }

    // ---- epilogue: C/D layout col=lane&15, row=(lane>>4)*4+reg (m89/m91)
    // K-split partials merge order-free via device-scope atomicAdd (P zeroed).
#pragma unroll
    for (int i = 0; i < 2; ++i) {
        const int row = m0 + wr * 32 + i * 16 + lkq * 4;
#pragma unroll
        for (int j = 0; j < 4; ++j) {
            const int col = n0 + wc * 64 + j * 16 + lrow;
#pragma unroll
            for (int rr = 0; rr < 4; ++rr)
                atomicAdd(&P[(size_t)(row + rr) * N + col], acc[i][j][rr]);
        }
    }
}

// ---------------------------------------------------------------------------
// Kernel 2: gate. s = sigmoid(P+bias); group-limited top-8; renormalize.
// One wave per row; lane l owns experts 4l..4l+3. Stable ties (lower index).
// ---------------------------------------------------------------------------
__global__ __launch_bounds__(256) void gate_topk(
        const float* __restrict__ P, const float* __restrict__ bias,
        float* __restrict__ out_w, float* __restrict__ out_i) {
    const int row = blockIdx.x * 4 + (threadIdx.x >> 6);
    const int lane = threadIdx.x & 63;

    const float4 a4 = *reinterpret_cast<const float4*>(P + (size_t)row * N + lane * 4);
    const float4 bb = *reinterpret_cast<const float4*>(bias + lane * 4);
    float v[4] = {1.f / (1.f + expf(-(a4.x + bb.x))),
                  1.f / (1.f + expf(-(a4.y + bb.y))),
                  1.f / (1.f + expf(-(a4.z + bb.z))),
                  1.f / (1.f + expf(-(a4.w + bb.w)))};

    // per-lane top-2 (values) for the group score
    float t1 = v[0], t2 = -1.f;
#pragma unroll
    for (int j = 1; j < 4; ++j) {
        if (v[j] > t1) { t2 = t1; t1 = v[j]; }
        else if (v[j] > t2) { t2 = v[j]; }
    }
#pragma unroll
    for (int m = 1; m <= 4; m <<= 1) {
        const float o1 = __shfl_xor(t1, m, 64);
        const float o2 = __shfl_xor(t2, m, 64);
        const float n1 = fmaxf(t1, o1);
        const float n2 = fmaxf(fminf(t1, o1), fmaxf(t2, o2));
        t1 = n1; t2 = n2;
    }
    float gs = t1 + t2;
    int gid = lane >> 3;
#pragma unroll
    for (int m = 8; m <= 32; m <<= 1) {
        const float og = __shfl_xor(gs, m, 64);
        const int oi = __shfl_xor(gid, m, 64);
        if (og > gs || (og == gs && oi < gid)) { gs = og; gid = oi; }
    }

    const bool inG = ((lane >> 3) == gid);
    if (!inG) { v[0] = v[1] = v[2] = v[3] = -1.f; }

    float wv[8];
    int wi[8];
#pragma unroll
    for (int r = 0; r < 8; ++r) {
        float bv = v[0]; int bj = 0;
#pragma unroll
        for (int j = 1; j < 4; ++j)
            if (v[j] > bv) { bv = v[j]; bj = j; }
        int be = lane * 4 + bj;
#pragma unroll
        for (int m = 1; m <= 32; m <<= 1) {
            const float ov = __shfl_xor(bv, m, 64);
            const int oe = __shfl_xor(be, m, 64);
            if (ov > bv || (ov == bv && oe < be)) { bv = ov; be = oe; }
        }
        wv[r] = bv; wi[r] = be;
        if ((be >> 2) == lane) v[be & 3] = -1.f;
    }

    float sum = 0.f;
#pragma unroll
    for (int r = 0; r < 8; ++r) sum += wv[r];

    if (lane == 0) {
#pragma unroll
        for (int r = 0; r < 8; ++r) {
            out_w[(size_t)row * TOPK + r] = wv[r] / sum * ROUTE_SCALE;
            out_i[(size_t)row * TOPK + r] = (float)wi[r];
        }
    }
}

// ---------------------------------------------------------------------------
extern "C" void kernel_launch(void* const* d_in, const int* in_sizes, int n_in,
                              void* d_out, int out_size, void* d_ws, size_t ws_size,
                              hipStream_t stream) {
    const float* x = (const float*)d_in[0];   // [M,K]
    const float* w = (const float*)d_in[1];   // [N,K]
    const float* b = (const float*)d_in[2];   // [N]

    // ws layout (15.3 MB): Wh | Wl | P
    char* ws = (char*)d_ws;
    _Float16* Wh = (_Float16*)ws;                              // 3,670,016 B
    _Float16* Wl = (_Float16*)(ws + 3670016);                  // 3,670,016 B
    float* P = (float*)(ws + 7340032);                         // 8,388,608 B

    float* out_w = (float*)d_out;
    float* out_i = out_w + (size_t)M * TOPK;

    zero_p<<<(M * N / 4) / 256, 256, 0, stream>>>((float4*)P);
    convert_w<<<(N * K / 4) / 256, 256, 0, stream>>>(w, Wh, Wl);
    gemm_split<<<768, 256, 0, stream>>>(x, Wh, Wl, P);
    gate_topk<<<M / 4, 256, 0, stream>>>(P, b, out_w, out_i);
}